// Round 6
// baseline (406.326 us; speedup 1.0000x reference)
//
#include <hip/hip_runtime.h>
#include <hip/hip_cooperative_groups.h>
#include <math.h>

namespace cg = cooperative_groups;

// Problem constants
#define BB 8
#define CC 64
#define TT 512
#define FF 256

typedef float floatx4 __attribute__((ext_vector_type(4)));

constexpr int TOFF = BB * FF;                       // 2048
constexpr int COFF = BB * FF + BB * TT;             // 6144
constexpr int NSUM = BB * FF + BB * TT + BB * CC;   // 6656 floats

struct PoolShm  { float tr[16][257]; float freq[256]; float cw[4]; };
struct GateShm  { float s[512]; float h[512]; };
struct ApplyShm { float g[NSUM]; };
union  Shm { PoolShm p; GateShm g; ApplyShm a; };   // 26.6 KB max

// ---------------------------------------------------------------------------
// Pool phase: one contiguous 64KB chunk (64 rows of F=256) -> register-only
// inner loop; cross-lane reduction once per chunk (logic verified in R4).
// ---------------------------------------------------------------------------
__device__ __forceinline__ void pool_phase(const floatx4* __restrict__ x4,
                                           float* __restrict__ sums,
                                           PoolShm& p, int chunk,
                                           int tid, int lane, int wid) {
    const int b     = chunk >> 9;          // 512 chunks per batch
    const int ch    = chunk & 511;
    const int c     = ch >> 3;             // chunk never crosses c
    const int tbase = (ch & 7) * 64;
    const long base = (long)chunk * 4096 + wid * 1024 + lane;

    float a0 = 0.f, a1 = 0.f, a2 = 0.f, a3 = 0.f;   // freq partials
    float ach[16];                                  // per-row sums (time)
    #pragma unroll
    for (int k = 0; k < 16; ++k) {
        floatx4 d = x4[base + k * 64];              // temporal: fill L3
        a0 += d.x; a1 += d.y; a2 += d.z; a3 += d.w;
        ach[k] = (d.x + d.y) + (d.z + d.w);
    }
    float csum = 0.f;
    #pragma unroll
    for (int k = 0; k < 16; ++k) csum += ach[k];
    #pragma unroll
    for (int o = 32; o > 0; o >>= 1) csum += __shfl_xor(csum, o, 64);

    __syncthreads();                       // LDS safe to overwrite
    p.freq[tid] = 0.f;
    #pragma unroll
    for (int k = 0; k < 16; ++k) p.tr[k][tid] = ach[k];
    if (lane == 0) p.cw[wid] = csum;
    __syncthreads();

    // freq: 4-way LDS atomic contention (4 waves share each f slot)
    atomicAdd(&p.freq[4 * lane + 0], a0);
    atomicAdd(&p.freq[4 * lane + 1], a1);
    atomicAdd(&p.freq[4 * lane + 2], a2);
    atomicAdd(&p.freq[4 * lane + 3], a3);

    // time: slot s (= row in chunk, t = tbase+s) summed by 4 threads
    {
        const int s = tid >> 2, q = tid & 3;
        float v = 0.f;
        #pragma unroll
        for (int j = 0; j < 16; ++j)
            v += p.tr[s & 15][(s >> 4) * 64 + q * 16 + j];
        v += __shfl_xor(v, 1, 64);
        v += __shfl_xor(v, 2, 64);
        if (q == 0) atomicAdd(&sums[TOFF + b * TT + tbase + s], v);
    }
    __syncthreads();

    atomicAdd(&sums[b * FF + tid], p.freq[tid]);
    if (tid == 0)
        atomicAdd(&sums[COFF + b * CC + c],
                  (p.cw[0] + p.cw[1]) + (p.cw[2] + p.cw[3]));
}

// ---------------------------------------------------------------------------
// Gate phase (256 threads, bid < 24): sigmoid(relu(mean @ W1^T) @ W2^T).
// ---------------------------------------------------------------------------
__device__ __forceinline__ void gate_phase(
    const float* __restrict__ w1f, const float* __restrict__ w2f,
    const float* __restrict__ w1t, const float* __restrict__ w2t,
    const float* __restrict__ w1c, const float* __restrict__ w2c,
    const float* __restrict__ sums, float* __restrict__ gates,
    GateShm& gs, int bid, int tid) {
    const int g = bid >> 3;
    const int b = bid & 7;
    int dim; const float *w1, *w2, *sin_; float* gout; float inv;
    if (g == 0) {
        dim = FF; w1 = w1f; w2 = w2f;
        sin_ = sums + b * FF; gout = gates + b * FF;
        inv = 1.f / (float)(CC * TT);
    } else if (g == 1) {
        dim = TT; w1 = w1t; w2 = w2t;
        sin_ = sums + TOFF + b * TT; gout = gates + TOFF + b * TT;
        inv = 1.f / (float)(CC * FF);
    } else {
        dim = CC; w1 = w1c; w2 = w2c;
        sin_ = sums + COFF + b * CC; gout = gates + COFF + b * CC;
        inv = 1.f / (float)(TT * FF);
    }
    for (int i = tid; i < dim; i += 256) gs.s[i] = sin_[i] * inv;
    __syncthreads();
    for (int row = tid; row < dim; row += 256) {
        const floatx4* __restrict__ wr = (const floatx4*)(w1 + (long)row * dim);
        const floatx4* __restrict__ sv = (const floatx4*)gs.s;
        float c0 = 0.f, c1 = 0.f, c2 = 0.f, c3 = 0.f;
        for (int j = 0; j < dim / 4; ++j) {
            floatx4 w = wr[j]; floatx4 s = sv[j];
            c0 += w.x * s.x; c1 += w.y * s.y; c2 += w.z * s.z; c3 += w.w * s.w;
        }
        gs.h[row] = fmaxf((c0 + c1) + (c2 + c3), 0.f);
    }
    __syncthreads();
    for (int row = tid; row < dim; row += 256) {
        const floatx4* __restrict__ wr = (const floatx4*)(w2 + (long)row * dim);
        const floatx4* __restrict__ hv = (const floatx4*)gs.h;
        float c0 = 0.f, c1 = 0.f, c2 = 0.f, c3 = 0.f;
        for (int j = 0; j < dim / 4; ++j) {
            floatx4 w = wr[j]; floatx4 h = hv[j];
            c0 += w.x * h.x; c1 += w.y * h.y; c2 += w.z * h.z; c3 += w.w * h.w;
        }
        gout[row] = 1.f / (1.f + expf(-((c0 + c1) + (c2 + c3))));
    }
}

// ---------------------------------------------------------------------------
// Apply phase: out = x * (fm + tm + cm + 1), descending address order so the
// read front chases pool's MRU L3 content ahead of out-write evictions.
// LOG_NBT = log2(total threads). Per-thread constants f4, t, cb.
// ---------------------------------------------------------------------------
template <int LOG_NBT>
__device__ __forceinline__ void apply_phase(const floatx4* __restrict__ x4,
                                            const float* __restrict__ gts,
                                            float* __restrict__ out,
                                            long base3) {
    floatx4* __restrict__ o4 = (floatx4*)out;
    constexpr int ITER  = 1 << (24 - LOG_NBT);
    constexpr int CSTEP = 1 << (LOG_NBT - 15);
    const int f4 = (int)(base3 & 63);
    const int t  = (int)((base3 >> 6) & (TT - 1));
    const int cb = (int)((base3 >> 15) & (CC - 1));
    #pragma unroll 8
    for (int k = ITER - 1; k >= 0; --k) {
        const int b = k >> (21 - LOG_NBT);
        const int c = (cb + k * CSTEP) & (CC - 1);
        const floatx4 fm = ((const floatx4*)(gts + b * FF))[f4];
        const float gadd = gts[TOFF + b * TT + t]
                         + gts[COFF + b * CC + c] + 1.0f;
        const long v = base3 + ((long)k << LOG_NBT);
        floatx4 d = x4[v];                           // L3-hit candidate
        floatx4 o = d * (fm + gadd);
        __builtin_nontemporal_store(o, &o4[v]);      // don't evict x
    }
}

// ---------------------------------------------------------------------------
// Fused cooperative kernel: 512 blocks x 256 (needs only 2 blocks/CU; LDS
// 26.6KB -> 6/CU, VGPR<=128 -> 4/CU: 2x capacity margin vs R5's exact fit).
// ---------------------------------------------------------------------------
__global__ __launch_bounds__(256, 4) void se_fused_kernel(
    const float* __restrict__ x,
    const float* __restrict__ w1f, const float* __restrict__ w2f,
    const float* __restrict__ w1t, const float* __restrict__ w2t,
    const float* __restrict__ w1c, const float* __restrict__ w2c,
    float* __restrict__ sums, float* __restrict__ gates,
    float* __restrict__ out)
{
    __shared__ Shm u;
    const int tid  = threadIdx.x;
    const int lane = tid & 63;
    const int wid  = tid >> 6;
    const int bid  = blockIdx.x;
    cg::grid_group grid = cg::this_grid();
    const floatx4* __restrict__ x4 = (const floatx4*)x;

    for (int rep = 0; rep < 8; ++rep)
        pool_phase(x4, sums, u.p, rep * 512 + bid, tid, lane, wid);

    __threadfence();
    grid.sync();

    if (bid < 24)
        gate_phase(w1f, w2f, w1t, w2t, w1c, w2c, sums, gates, u.g, bid, tid);

    __threadfence();
    grid.sync();

    // preload all gates into LDS (first touch after sync -> coherent)
    for (int i = tid; i < NSUM; i += 256) u.a.g[i] = gates[i];
    __syncthreads();
    apply_phase<17>(x4, u.a.g, out, (long)bid * 256 + tid);
}

// ---------------------------------------------------------------------------
// Fallback path (3 kernels, R4-verified structure)
// ---------------------------------------------------------------------------
__global__ __launch_bounds__(256) void zero_k(float* __restrict__ sums) {
    const int i = blockIdx.x * 256 + threadIdx.x;
    if (i < NSUM) sums[i] = 0.f;
}

__global__ __launch_bounds__(256) void pool_k(const float* __restrict__ x,
                                              float* __restrict__ sums) {
    __shared__ PoolShm p;
    const int tid = threadIdx.x;
    pool_phase((const floatx4*)x, sums, p, blockIdx.x, tid, tid & 63, tid >> 6);
}

__global__ __launch_bounds__(256) void gate_k(
    const float* __restrict__ w1f, const float* __restrict__ w2f,
    const float* __restrict__ w1t, const float* __restrict__ w2t,
    const float* __restrict__ w1c, const float* __restrict__ w2c,
    const float* __restrict__ sums, float* __restrict__ gates) {
    __shared__ GateShm gs;
    gate_phase(w1f, w2f, w1t, w2t, w1c, w2c, sums, gates, gs,
               blockIdx.x, threadIdx.x);
}

__global__ __launch_bounds__(256) void apply_k(const float* __restrict__ x,
                                               const float* __restrict__ gates,
                                               float* __restrict__ out) {
    apply_phase<19>((const floatx4*)x, gates, out,
                    (long)blockIdx.x * 256 + threadIdx.x);
}

extern "C" void kernel_launch(void* const* d_in, const int* in_sizes, int n_in,
                              void* d_out, int out_size, void* d_ws, size_t ws_size,
                              hipStream_t stream) {
    const float* x   = (const float*)d_in[0];
    const float* w1f = (const float*)d_in[1];
    const float* w2f = (const float*)d_in[2];
    const float* w1t = (const float*)d_in[3];
    const float* w2t = (const float*)d_in[4];
    const float* w1c = (const float*)d_in[5];
    const float* w2c = (const float*)d_in[6];
    float* out = (float*)d_out;

    float* sums  = (float*)d_ws;
    float* gates = sums + NSUM;

    zero_k<<<(NSUM + 255) / 256, 256, 0, stream>>>(sums);

    // Pre-gate the cooperative launch on actual occupancy (graph-safe queries).
    int dev = 0, nCU = 0, maxB = 0;
    bool coop = (hipGetDevice(&dev) == hipSuccess) &&
                (hipDeviceGetAttribute(&nCU, hipDeviceAttributeMultiprocessorCount,
                                       dev) == hipSuccess) &&
                (hipOccupancyMaxActiveBlocksPerMultiprocessor(
                     &maxB, se_fused_kernel, 256, 0) == hipSuccess) &&
                ((long)maxB * nCU >= 512);
    if (coop) {
        void* args[] = {
            (void*)&x, (void*)&w1f, (void*)&w2f, (void*)&w1t, (void*)&w2t,
            (void*)&w1c, (void*)&w2c, (void*)&sums, (void*)&gates, (void*)&out
        };
        if (hipLaunchCooperativeKernel(se_fused_kernel, dim3(512), dim3(256),
                                       args, 0, stream) != hipSuccess)
            coop = false;
    }
    if (!coop) {
        pool_k<<<4096, 256, 0, stream>>>(x, sums);
        gate_k<<<24, 256, 0, stream>>>(w1f, w2f, w1t, w2t, w1c, w2c, sums, gates);
        apply_k<<<2048, 256, 0, stream>>>(x, gates, out);
    }
}

// Round 7
// 203.852 us; speedup vs baseline: 1.9932x; 1.9932x over previous
//
#include <hip/hip_runtime.h>
#include <math.h>

// Problem constants
#define BB 8
#define CC 64
#define TT 512
#define FF 256

typedef float floatx4 __attribute__((ext_vector_type(4)));

constexpr int TOFF = BB * FF;                       // 2048
constexpr int COFF = BB * FF + BB * TT;             // 6144
constexpr int NSUM = BB * FF + BB * TT + BB * CC;   // 6656 floats

// ws layout (floats)
constexpr long PF_OFF = 0;                          // Pfreq [4096][256]
constexpr long PT_OFF = PF_OFF + 4096L * 256;       // Ptime [4096][64]
constexpr long PC_OFF = PT_OFF + 4096L * 64;        // Pch   [4096]
constexpr long G_OFF  = PC_OFF + 4096;              // gates [NSUM]

// ---------------------------------------------------------------------------
// Kernel 1: pool. One contiguous 64KB chunk (64 rows of F=256) per block.
// Register-only inner loop (R4-verified); epilogue writes PARTIALS with plain
// stores (no atomics -> no zeroing pass, deterministic sums).
// chunk = b*512 + c*8 + (t>>6); rows of chunk = 64 consecutive t of one c.
// Loads are temporal ON PURPOSE: x (256MB) fills the 256MB L3 so apply's
// re-read hits L3 (confirmed R6: apply fetched only ~16MB from HBM).
// ---------------------------------------------------------------------------
__global__ __launch_bounds__(256) void pool_k(const float* __restrict__ x,
                                              float* __restrict__ pf,
                                              float* __restrict__ pt,
                                              float* __restrict__ pc) {
    __shared__ float tr[16][257];
    __shared__ float fr[256];
    __shared__ float cw[4];
    const int tid  = threadIdx.x;
    const int lane = tid & 63;
    const int wid  = tid >> 6;
    const int chunk = blockIdx.x;                    // 0..4095

    const floatx4* __restrict__ x4 = (const floatx4*)x;
    const long base = (long)chunk * 4096 + wid * 1024 + lane;

    float a0 = 0.f, a1 = 0.f, a2 = 0.f, a3 = 0.f;    // freq partials
    float ach[16];                                   // row sums (time)
    #pragma unroll
    for (int k = 0; k < 16; ++k) {
        floatx4 d = x4[base + k * 64];               // temporal: fill L3
        a0 += d.x; a1 += d.y; a2 += d.z; a3 += d.w;
        ach[k] = (d.x + d.y) + (d.z + d.w);
    }
    float csum = 0.f;
    #pragma unroll
    for (int k = 0; k < 16; ++k) csum += ach[k];
    #pragma unroll
    for (int o = 32; o > 0; o >>= 1) csum += __shfl_xor(csum, o, 64);

    fr[tid] = 0.f;
    #pragma unroll
    for (int k = 0; k < 16; ++k) tr[k][tid] = ach[k];
    if (lane == 0) cw[wid] = csum;
    __syncthreads();

    // freq: aggregate across the 4 waves sharing each f slot (LDS atomics)
    atomicAdd(&fr[4 * lane + 0], a0);
    atomicAdd(&fr[4 * lane + 1], a1);
    atomicAdd(&fr[4 * lane + 2], a2);
    atomicAdd(&fr[4 * lane + 3], a3);

    // time: row s of chunk summed by 4 threads (q), then 2 shuffles
    {
        const int s = tid >> 2, q = tid & 3;
        float v = 0.f;
        #pragma unroll
        for (int j = 0; j < 16; ++j)
            v += tr[s & 15][(s >> 4) * 64 + q * 16 + j];
        v += __shfl_xor(v, 1, 64);
        v += __shfl_xor(v, 2, 64);
        if (q == 0) pt[chunk * 64 + s] = v;          // plain store
    }
    __syncthreads();

    pf[chunk * 256 + tid] = fr[tid];                 // plain store
    if (tid == 0) pc[chunk] = (cw[0] + cw[1]) + (cw[2] + cw[3]);
}

// ---------------------------------------------------------------------------
// Kernel 2: reduce partials + SE gate MLPs. 24 blocks x 512 threads.
// gate = sigmoid( relu( mean @ W1^T ) @ W2^T )
// ---------------------------------------------------------------------------
__global__ __launch_bounds__(512) void gate_k(
    const float* __restrict__ w1f, const float* __restrict__ w2f,
    const float* __restrict__ w1t, const float* __restrict__ w2t,
    const float* __restrict__ w1c, const float* __restrict__ w2c,
    const float* __restrict__ pf, const float* __restrict__ pt,
    const float* __restrict__ pc, float* __restrict__ gates) {
    __shared__ __align__(16) float s[512];
    __shared__ __align__(16) float h[512];
    const int g = blockIdx.x >> 3;
    const int b = blockIdx.x & 7;
    const int tid = threadIdx.x;

    int dim; const float *w1, *w2; float* gout; float inv;
    if (g == 0) { dim = FF; w1 = w1f; w2 = w2f; gout = gates + b * FF;
                  inv = 1.f / (float)(CC * TT); }
    else if (g == 1) { dim = TT; w1 = w1t; w2 = w2t; gout = gates + TOFF + b * TT;
                  inv = 1.f / (float)(CC * FF); }
    else { dim = CC; w1 = w1c; w2 = w2c; gout = gates + COFF + b * CC;
                  inv = 1.f / (float)(TT * FF); }

    // ---- reduce partials into s[0..dim) ----
    if (g == 0) {
        // Pfreq[b*512+ch][f]: two half-sums via h[], then combine.
        const int f = tid & 255, half = tid >> 8;
        float acc = 0.f;
        const float* __restrict__ p = pf + ((long)(b * 512 + half * 256) * 256) + f;
        #pragma unroll 8
        for (int ch = 0; ch < 256; ++ch) acc += p[(long)ch * 256];
        h[tid] = acc;
        __syncthreads();
        if (tid < 256) s[tid] = (h[tid] + h[tid + 256]) * inv;
    } else if (g == 1) {
        // Ptime[b*512 + c*8 + (t>>6)][t&63], sum over c
        const int t = tid;
        float acc = 0.f;
        const float* __restrict__ p = pt + ((long)(b * 512 + (t >> 6)) * 64) + (t & 63);
        #pragma unroll 8
        for (int c = 0; c < 64; ++c) acc += p[(long)c * 8 * 64];
        s[t] = acc * inv;
    } else {
        if (tid < CC) {
            float acc = 0.f;
            #pragma unroll
            for (int j = 0; j < 8; ++j) acc += pc[b * 512 + tid * 8 + j];
            s[tid] = acc * inv;
        }
    }
    __syncthreads();

    // ---- layer 1: relu(s @ W1^T) ----
    for (int row = tid; row < dim; row += 512) {
        const floatx4* __restrict__ wr = (const floatx4*)(w1 + (long)row * dim);
        const floatx4* __restrict__ sv = (const floatx4*)s;
        float c0 = 0.f, c1 = 0.f, c2 = 0.f, c3 = 0.f;
        for (int j = 0; j < dim / 4; ++j) {
            floatx4 w = wr[j]; floatx4 sj = sv[j];
            c0 += w.x * sj.x; c1 += w.y * sj.y; c2 += w.z * sj.z; c3 += w.w * sj.w;
        }
        h[row] = fmaxf((c0 + c1) + (c2 + c3), 0.f);
    }
    __syncthreads();
    // ---- layer 2: sigmoid(h @ W2^T) ----
    for (int row = tid; row < dim; row += 512) {
        const floatx4* __restrict__ wr = (const floatx4*)(w2 + (long)row * dim);
        const floatx4* __restrict__ hv = (const floatx4*)h;
        float c0 = 0.f, c1 = 0.f, c2 = 0.f, c3 = 0.f;
        for (int j = 0; j < dim / 4; ++j) {
            floatx4 w = wr[j]; floatx4 hj = hv[j];
            c0 += w.x * hj.x; c1 += w.y * hj.y; c2 += w.z * hj.z; c3 += w.w * hj.w;
        }
        gout[row] = 1.f / (1.f + expf(-((c0 + c1) + (c2 + c3))));
    }
}

// ---------------------------------------------------------------------------
// Kernel 3: out = x * (fm + tm + cm + 1). DESCENDING address order: pool left
// L3 full of x (MRU = high addresses); out-write evictions take LRU (low), so
// the high->low read front stays ahead of eviction (R6: ~94% L3 hits).
// nt store: out must not displace x more than necessary.
// v = base3 + k*2^19: f4, t, cb are per-thread constants.
// ---------------------------------------------------------------------------
__global__ __launch_bounds__(256) void apply_k(const float* __restrict__ x,
                                               const float* __restrict__ gts,
                                               float* __restrict__ out) {
    const floatx4* __restrict__ x4 = (const floatx4*)x;
    floatx4* __restrict__ o4 = (floatx4*)out;
    const long base3 = (long)blockIdx.x * 256 + threadIdx.x;   // < 2^19
    const int f4 = (int)(base3 & 63);
    const int t  = (int)((base3 >> 6) & (TT - 1));
    const int cb = (int)((base3 >> 15) & (CC - 1));
    #pragma unroll 8
    for (int k = 31; k >= 0; --k) {
        const int b = k >> 2;
        const int c = (cb + k * 16) & (CC - 1);
        const floatx4 fm = ((const floatx4*)(gts + b * FF))[f4];
        const float gadd = gts[TOFF + b * TT + t]
                         + gts[COFF + b * CC + c] + 1.0f;
        const long v = base3 + ((long)k << 19);
        floatx4 d = x4[v];                           // mostly L3 hits
        floatx4 o = d * (fm + gadd);
        __builtin_nontemporal_store(o, &o4[v]);
    }
}

extern "C" void kernel_launch(void* const* d_in, const int* in_sizes, int n_in,
                              void* d_out, int out_size, void* d_ws, size_t ws_size,
                              hipStream_t stream) {
    const float* x   = (const float*)d_in[0];
    const float* w1f = (const float*)d_in[1];
    const float* w2f = (const float*)d_in[2];
    const float* w1t = (const float*)d_in[3];
    const float* w2t = (const float*)d_in[4];
    const float* w1c = (const float*)d_in[5];
    const float* w2c = (const float*)d_in[6];
    float* out = (float*)d_out;

    float* ws    = (float*)d_ws;
    float* pf    = ws + PF_OFF;
    float* pt    = ws + PT_OFF;
    float* pc    = ws + PC_OFF;
    float* gates = ws + G_OFF;

    pool_k<<<4096, 256, 0, stream>>>(x, pf, pt, pc);
    gate_k<<<24, 512, 0, stream>>>(w1f, w2f, w1t, w2t, w1c, w2c,
                                   pf, pt, pc, gates);
    apply_k<<<2048, 256, 0, stream>>>(x, gates, out);
}